// Round 9
// baseline (695.856 us; speedup 1.0000x reference)
//
#include <hip/hip_runtime.h>

#define HDIM   64
#define TSTEPS 5
#define WAVES  8
#define BLOCK  (WAVES * 64)     // 512 threads
#define EPW    16               // batch per wave = MFMA N (transposed form)
#define EPB    (WAVES * EPW)    // 128 batch per block

typedef _Float16 f16x8 __attribute__((ext_vector_type(8)));
typedef _Float16 f16x2 __attribute__((ext_vector_type(2)));
typedef float    f32x4 __attribute__((ext_vector_type(4)));
typedef int      i32x4 __attribute__((ext_vector_type(4)));

#define L2E 1.44269504088896340736f   // log2(e)

__device__ __forceinline__ float rcp_(float x) { return __builtin_amdgcn_rcpf(x); }
__device__ __forceinline__ float ex2_(float x) { return __builtin_amdgcn_exp2f(x); }

// TRANSPOSED formulation (round 9): gates^T = W_hh * h^T.
//   A = W_hh fragments (the SAME staged Wf bytes as the old B-role: both store
//       W_hh[j][k] at lane (j&15, k-quad) — A-frag m=lane&15 ≡ B-frag n=lane&15).
//   B = h^T: lane holds B[k=kh*32+q*8+i][e=lane&15]  (q=lane>>4, i=0..7)
//   D: lane holds D[jrow=q*4+reg][e=lane&15] per 16x16 tile; tile n=4G+tt
//      covers gate rows G*64 + 16tt + [0,16). Activation is lane-local, chunked
//      over tt with 16 accs live — structurally identical to rounds 0-8.
// The D -> next-B transpose is now a REGISTER permutation (no LDS hbuf):
//   pack pairs: hpk[tt][s] = f16x2(h[j_h=16tt+4q+2s], h[j_h+1])  (8 b32)
//   B[kh].w = sel(q<2, shfl(hpk[2kh][w&1], Lw), shfl(hpk[2kh+1][w&1], Lw))
//   Lw = 16*((2q + (w>>1)) & 3) + e      (L0 for w<2, L1 for w>=2)
// Verified by element-chase: (j_h=13,e=5)->B0.2@lane21-hi, (62,63)->B1.3, etc.
// Deletes hbuf (16 KB LDS), 16 ds_write + 2 ds_read_b128 per t, 3 of 4 x loads.
// LDS 51.7 -> ~34.3 KB  =>  4 blocks/CU = 32 waves/CU (was 24): the occupancy
// lever that does NOT fight the VGPR cliff.
//
// ACTIVATION: round-8 form (5 ex2 + 2 rcp, paired rcp). Trans-count levers are
// exhausted: 10->8->7 trans/u each moved <=2% (trans is ~half-rate, a rcp<->2
// full-rate swap is issue-neutral).
//
// REGISTER/OCCUPANCY MODEL (rounds 1-8, confirmed):
//   compiler VGPR cap = 256/arg2 (8->32, 4->64, 3->85, 2->128); allocator
//   EXPANDS into whatever cap it gets (r4: took 124 of 128) -> pin arg2=4.
//   Residency: 512 VGPR/SIMD pool; 32 waves/CU needs VGPR<=64 AND LDS<=40KB.
//   DEAD ENDS: WAVES=16; arg2<=3 with fat live set (spill: r2/3/5 ~1.4 GB
//   scratch); hoisted coeff arrays; global common-denominator activation.
__global__ __launch_bounds__(BLOCK, 4) void lstm_mfma_kernel(
    const float* __restrict__ x,      // [B, T, 1]
    const float* __restrict__ W_ih,   // [256, 1]
    const float* __restrict__ W_hh,   // [256, 64]
    const float* __restrict__ b_ih,   // [256]
    const float* __restrict__ b_hh,   // [256]
    const float* __restrict__ W_fc,   // [1, 64]
    const float* __restrict__ b_fc,   // [1]
    float* __restrict__ out,          // [B, 1]
    int B)
{
    __shared__ _Float16 Wf[2048 * 8];   // 32 KB, W_hh fragments (A-role now)
    __shared__ float    wih_s[256];     // 1 KB (pre-scaled)
    __shared__ float    cb_s[256];      // 1 KB (pre-scaled b_ih + b_hh)
    __shared__ float    wfc_s[64];      // 256 B (FC weights)

    const int tid = threadIdx.x;

    // ---- one-time staging: identical bytes to rounds 0-8 ----
    #pragma unroll
    for (int s0 = 0; s0 < 2048; s0 += BLOCK) {
        const int s  = s0 + tid;
        const int ln = s & 63;
        const int kh = (s >> 6) & 1;
        const int n  = s >> 7;                             // tile 0..15, gate G = n>>2
        const float scl = ((n >> 2) == 2) ? (2.0f * L2E) : L2E;
        const int j  = n * 16 + (ln & 15);                 // gate row
        const int k0 = kh * 32 + ((ln >> 4) & 3) * 8;      // hidden k
        const float* src = W_hh + j * HDIM + k0;
        #pragma unroll
        for (int i = 0; i < 8; i++)
            Wf[s * 8 + i] = (_Float16)(src[i] * scl);
    }
    if (tid < 256) {
        const float scl = ((tid >> 6) == 2) ? (2.0f * L2E) : L2E;
        wih_s[tid] = W_ih[tid] * scl;
        cb_s[tid]  = (b_ih[tid] + b_hh[tid]) * scl;
    }
    if (tid < 64) wfc_s[tid] = W_fc[tid];
    __syncthreads();   // only barrier in the kernel

    const int lane = tid & 63;
    const int wave = tid >> 6;
    const int e    = lane & 15;    // batch index within wave (MFMA N position)
    const int q    = lane >> 4;    // quad
    const int eg0  = (blockIdx.x * WAVES + wave) * EPW;

    int eg = eg0 + e; if (eg >= B) eg = B - 1;
    const float* xp = x + (long)eg * TSTEPS;   // per-t load = imm offset

    // shuffle source lanes for the h-transpose (computed once)
    const int L0 = (((q << 1)    ) & 3) * 16 + e;
    const int L1 = (((q << 1) + 1) & 3) * 16 + e;

    float c[16];      // cell state, 2L2E-scaled; [tt*4+reg] <-> j_h=16tt+4q+reg
    float pfc = 0.0f; // FC partial (t=4 only)
    int   hpk[4][2];  // packed h f16-pairs, rebuilt each t
    i32x4 bi[2];      // next-timestep B-fragments [kh]

    #pragma unroll
    for (int t = 0; t < TSTEPS; t++) {
        const float xt = xp[t];

        f16x8 b0, b1;
        if (t > 0) {
            b0 = __builtin_bit_cast(f16x8, bi[0]);
            b1 = __builtin_bit_cast(f16x8, bi[1]);
        }

        #pragma unroll
        for (int tt = 0; tt < 4; tt++) {       // j_h chunk: rows 16tt+4q+reg
            // C-init: bias + x*W_ih as the MFMA C operand (LDS broadcasts)
            f32x4 ag[4];
            #pragma unroll
            for (int G = 0; G < 4; G++)
                #pragma unroll
                for (int r = 0; r < 4; r++) {
                    const int j = G * 64 + tt * 16 + q * 4 + r;
                    ag[G][r] = fmaf(xt, wih_s[j], cb_s[j]);
                }

            if (t > 0) {
                #pragma unroll
                for (int G = 0; G < 4; G++) {
                    const int n = G * 4 + tt;          // same Wf tiles as before
                    f16x8 w0 = *(const f16x8*)(Wf + (n * 2 + 0) * 512 + lane * 8);
                    f16x8 w1 = *(const f16x8*)(Wf + (n * 2 + 1) * 512 + lane * 8);
                    // operands SWAPPED vs rounds 0-8: A=W_hh, B=h^T
                    ag[G] = __builtin_amdgcn_mfma_f32_16x16x32_f16(w0, b0, ag[G], 0, 0, 0);
                    ag[G] = __builtin_amdgcn_mfma_f32_16x16x32_f16(w1, b1, ag[G], 0, 0, 0);
                }
            }

            float hv4[4];
            #pragma unroll
            for (int r = 0; r < 4; r++) {
                const int u = tt * 4 + r;
                const float Ei = ex2_(-ag[0][r]);
                const float Eg = ex2_(ag[2][r]);
                const float a  = (1.0f + Ei) * (Eg + 1.0f);
                const float gn = (2.0f * L2E) * (Eg - 1.0f);
                float cs;
                if (t > 0) {
                    // paired rcp: one v_rcp serves i*tanh(g) and sigmoid(f)
                    const float Ef = ex2_(-ag[1][r]);
                    const float bb = 1.0f + Ef;
                    const float rr = rcp_(a * bb);
                    cs = fmaf(rr * a, c[u], gn * (rr * bb));
                } else {
                    cs = gn * rcp_(a);
                }
                c[u] = cs;                                // scaled domain
                const float Eo = ex2_(-ag[3][r]);
                const float Ec = ex2_(cs);
                hv4[r] = (Ec - 1.0f) * rcp_((1.0f + Eo) * (Ec + 1.0f));
            }

            if (t < TSTEPS - 1) {
                // pack adjacent j_h pairs for the register transpose
                f16x2 p0 = { (_Float16)hv4[0], (_Float16)hv4[1] };
                f16x2 p1 = { (_Float16)hv4[2], (_Float16)hv4[3] };
                hpk[tt][0] = __builtin_bit_cast(int, p0);
                hpk[tt][1] = __builtin_bit_cast(int, p1);
            } else {
                // FC inline: pfc += h[j_h][e] * W_fc[j_h]
                #pragma unroll
                for (int r = 0; r < 4; r++)
                    pfc = fmaf(hv4[r], wfc_s[tt * 16 + q * 4 + r], pfc);
            }
        }

        if (t < TSTEPS - 1) {
            // register-only h transpose -> next B-fragments (16 shfl + 8 sel)
            #pragma unroll
            for (int kh = 0; kh < 2; kh++) {
                const int a0 = hpk[2 * kh][0],     a1 = hpk[2 * kh][1];
                const int c0 = hpk[2 * kh + 1][0], c1 = hpk[2 * kh + 1][1];
                const int sA0 = __shfl(a0, L0, 64), sC0 = __shfl(c0, L0, 64);
                const int sA1 = __shfl(a1, L0, 64), sC1 = __shfl(c1, L0, 64);
                const int sB0 = __shfl(a0, L1, 64), sD0 = __shfl(c0, L1, 64);
                const int sB1 = __shfl(a1, L1, 64), sD1 = __shfl(c1, L1, 64);
                i32x4 v;
                v[0] = (q < 2) ? sA0 : sC0;   // w=0: k pair (8q+0,1)
                v[1] = (q < 2) ? sA1 : sC1;   // w=1: k pair (8q+2,3)
                v[2] = (q < 2) ? sB0 : sD0;   // w=2: k pair (8q+4,5)
                v[3] = (q < 2) ? sB1 : sD1;   // w=3: k pair (8q+6,7)
                bi[kh] = v;
            }
        }
    }

    // ---- FC epilogue: reduce over the 4 q-groups (j_h partition), write ----
    pfc += __shfl_xor(pfc, 16, 64);
    pfc += __shfl_xor(pfc, 32, 64);
    if (lane < 16) {
        const int eo = eg0 + lane;
        if (eo < B) out[eo] = pfc + b_fc[0];
    }
}

extern "C" void kernel_launch(void* const* d_in, const int* in_sizes, int n_in,
                              void* d_out, int out_size, void* d_ws, size_t ws_size,
                              hipStream_t stream) {
    const float* x    = (const float*)d_in[0];
    const float* W_ih = (const float*)d_in[1];
    const float* W_hh = (const float*)d_in[2];
    const float* b_ih = (const float*)d_in[3];
    const float* b_hh = (const float*)d_in[4];
    const float* W_fc = (const float*)d_in[5];
    const float* b_fc = (const float*)d_in[6];
    float* out = (float*)d_out;

    const int B = in_sizes[0] / TSTEPS;   // x is [B, T, 1]
    const int grid = (B + EPB - 1) / EPB;
    lstm_mfma_kernel<<<grid, BLOCK, 0, stream>>>(x, W_ih, W_hh, b_ih, b_hh,
                                                 W_fc, b_fc, out, B);
}

// Round 10
// 688.979 us; speedup vs baseline: 1.0100x; 1.0100x over previous
//
#include <hip/hip_runtime.h>

#define HDIM   64
#define TSTEPS 5
#define WAVES  8
#define BLOCK  (WAVES * 64)     // 512 threads
#define EPW    16               // batch per wave = MFMA N (transposed form)
#define EPB    (WAVES * EPW)    // 128 batch per block

typedef _Float16 f16x8 __attribute__((ext_vector_type(8)));
typedef _Float16 f16x2 __attribute__((ext_vector_type(2)));
typedef float    f32x4 __attribute__((ext_vector_type(4)));
typedef int      i32x4 __attribute__((ext_vector_type(4)));

#define L2E 1.44269504088896340736f   // log2(e)

__device__ __forceinline__ float rcp_(float x) { return __builtin_amdgcn_rcpf(x); }
__device__ __forceinline__ float ex2_(float x) { return __builtin_amdgcn_exp2f(x); }

// TRANSPOSED formulation (rounds 9-10): gates^T = W_hh * h^T.
//   A = W_hh fragments (same staged Wf bytes as the old B-role).
//   B = h^T: lane holds B[k=kh*32+q*8+i][e=lane&15]  (q=lane>>4, i=0..7)
//   D: lane holds D[jrow=q*4+reg][e=lane&15] per 16x16 tile n=4G+tt.
// Round-9 lesson: hpk[4][2] held ALL tt chunks' h-pairs live across the tt
// loop (+8 regs) -> 68 live > cap 64 -> spill (1.27 GB scratch). Fix: the
// B-fragment index algebra shows dest (q,kh) needs exactly ONE tt chunk
// (tt = 2kh + (q>=2)), so the 4 shuffles per tt run IMMEDIATELY after that
// chunk's activation; p0/p1 die inside the block. Same arithmetic as round 9
// (passed, absmax 9.8e-4), just reordered -> peak live ~58.
//   s0=shfl(p0,L0) s1=shfl(p1,L0) s2=shfl(p0,L1) s3=shfl(p1,L1)
//   take = (tt&1) ? q>=2 : q<2;   bi[tt>>1][w] = take ? s_w : keep
//   L0 = ((2q)&3)*16 + e,  L1 = ((2q+1)&3)*16 + e
// Also: ag-init and FC weights read as ds_read_b128 (8/tt, was 32 scalar).
// Deletes hbuf: LDS 51.7 -> 34.5 KB => 4 blocks/CU = 32 waves/CU possible.
//
// ACTIVATION: round-8 form (5 ex2 + 2 rcp, paired rcp). Trans-count levers
// exhausted (10->8->7 trans/u each moved <=2%: trans is ~half-rate here).
//
// REGISTER/OCCUPANCY MODEL (rounds 1-9, confirmed):
//   compiler VGPR cap = 256/arg2 (8->32, 4->64, 3->85, 2->128); allocator
//   EXPANDS into the cap -> pin arg2=4 (cap 64, at the residency cliff).
//   DEAD ENDS: WAVES=16; arg2<=3 with fat live set (spill); hoisted coeff
//   arrays; global common-denominator activation; whole-timestep hpk.
__global__ __launch_bounds__(BLOCK, 4) void lstm_mfma_kernel(
    const float* __restrict__ x,      // [B, T, 1]
    const float* __restrict__ W_ih,   // [256, 1]
    const float* __restrict__ W_hh,   // [256, 64]
    const float* __restrict__ b_ih,   // [256]
    const float* __restrict__ b_hh,   // [256]
    const float* __restrict__ W_fc,   // [1, 64]
    const float* __restrict__ b_fc,   // [1]
    float* __restrict__ out,          // [B, 1]
    int B)
{
    __shared__ _Float16 Wf[2048 * 8];   // 32 KB, W_hh fragments (A-role)
    __shared__ float    wih_s[256];     // 1 KB (pre-scaled)
    __shared__ float    cb_s[256];      // 1 KB (pre-scaled b_ih + b_hh)
    __shared__ float    wfc_s[64];      // 256 B (FC weights)

    const int tid = threadIdx.x;

    // ---- one-time staging: identical bytes to rounds 0-9 ----
    #pragma unroll
    for (int s0i = 0; s0i < 2048; s0i += BLOCK) {
        const int s  = s0i + tid;
        const int ln = s & 63;
        const int kh = (s >> 6) & 1;
        const int n  = s >> 7;                             // tile 0..15, gate G = n>>2
        const float scl = ((n >> 2) == 2) ? (2.0f * L2E) : L2E;
        const int j  = n * 16 + (ln & 15);                 // gate row
        const int k0 = kh * 32 + ((ln >> 4) & 3) * 8;      // hidden k
        const float* src = W_hh + j * HDIM + k0;
        #pragma unroll
        for (int i = 0; i < 8; i++)
            Wf[s * 8 + i] = (_Float16)(src[i] * scl);
    }
    if (tid < 256) {
        const float scl = ((tid >> 6) == 2) ? (2.0f * L2E) : L2E;
        wih_s[tid] = W_ih[tid] * scl;
        cb_s[tid]  = (b_ih[tid] + b_hh[tid]) * scl;
    }
    if (tid < 64) wfc_s[tid] = W_fc[tid];
    __syncthreads();   // only barrier in the kernel

    const int lane = tid & 63;
    const int wave = tid >> 6;
    const int e    = lane & 15;    // batch index within wave (MFMA N position)
    const int q    = lane >> 4;    // quad
    const int eg0  = (blockIdx.x * WAVES + wave) * EPW;

    int eg = eg0 + e; if (eg >= B) eg = B - 1;
    const float* xp = x + (long)eg * TSTEPS;   // per-t load = imm offset

    // shuffle source lanes for the h-transpose (computed once)
    const int L0 = (((q << 1)    ) & 3) * 16 + e;
    const int L1 = (((q << 1) + 1) & 3) * 16 + e;
    const bool qlo = (q < 2);

    float c[16];          // cell state, 2L2E-scaled; [tt*4+reg] <-> j_h=16tt+4q+reg
    float pfc = 0.0f;     // FC partial (t=4 only)
    i32x4 bi[2] = {};     // next-timestep B-fragments [kh]

    #pragma unroll
    for (int t = 0; t < TSTEPS; t++) {
        const float xt = xp[t];

        f16x8 b0, b1;
        if (t > 0) {
            b0 = __builtin_bit_cast(f16x8, bi[0]);
            b1 = __builtin_bit_cast(f16x8, bi[1]);
        }

        #pragma unroll
        for (int tt = 0; tt < 4; tt++) {       // j_h chunk: rows 16tt+4q+reg
            // C-init: bias + x*W_ih as the MFMA C operand (vector LDS reads)
            f32x4 ag[4];
            #pragma unroll
            for (int G = 0; G < 4; G++) {
                const f32x4 wih4 = *(const f32x4*)(wih_s + G * 64 + tt * 16 + q * 4);
                const f32x4 cb4  = *(const f32x4*)(cb_s  + G * 64 + tt * 16 + q * 4);
                #pragma unroll
                for (int r = 0; r < 4; r++)
                    ag[G][r] = fmaf(xt, wih4[r], cb4[r]);
            }

            if (t > 0) {
                #pragma unroll
                for (int G = 0; G < 4; G++) {
                    const int n = G * 4 + tt;          // same Wf tiles as before
                    f16x8 w0 = *(const f16x8*)(Wf + (n * 2 + 0) * 512 + lane * 8);
                    f16x8 w1 = *(const f16x8*)(Wf + (n * 2 + 1) * 512 + lane * 8);
                    // operands SWAPPED vs rounds 0-8: A=W_hh, B=h^T
                    ag[G] = __builtin_amdgcn_mfma_f32_16x16x32_f16(w0, b0, ag[G], 0, 0, 0);
                    ag[G] = __builtin_amdgcn_mfma_f32_16x16x32_f16(w1, b1, ag[G], 0, 0, 0);
                }
            }

            float hv4[4];
            #pragma unroll
            for (int r = 0; r < 4; r++) {
                const int u = tt * 4 + r;
                const float Ei = ex2_(-ag[0][r]);
                const float Eg = ex2_(ag[2][r]);
                const float a  = (1.0f + Ei) * (Eg + 1.0f);
                const float gn = (2.0f * L2E) * (Eg - 1.0f);
                float cs;
                if (t > 0) {
                    // paired rcp: one v_rcp serves i*tanh(g) and sigmoid(f)
                    const float Ef = ex2_(-ag[1][r]);
                    const float bb = 1.0f + Ef;
                    const float rr = rcp_(a * bb);
                    cs = fmaf(rr * a, c[u], gn * (rr * bb));
                } else {
                    cs = gn * rcp_(a);
                }
                c[u] = cs;                                // scaled domain
                const float Eo = ex2_(-ag[3][r]);
                const float Ec = ex2_(cs);
                hv4[r] = (Ec - 1.0f) * rcp_((1.0f + Eo) * (Ec + 1.0f));
            }

            if (t < TSTEPS - 1) {
                // INCREMENTAL register transpose: this tt's 4 h values ->
                // the one (kh, q-half) B-fragment slice that needs them.
                f16x2 p0v = { (_Float16)hv4[0], (_Float16)hv4[1] };
                f16x2 p1v = { (_Float16)hv4[2], (_Float16)hv4[3] };
                const int p0 = __builtin_bit_cast(int, p0v);
                const int p1 = __builtin_bit_cast(int, p1v);
                const int s0 = __shfl(p0, L0, 64);
                const int s1 = __shfl(p1, L0, 64);
                const int s2 = __shfl(p0, L1, 64);
                const int s3 = __shfl(p1, L1, 64);
                const bool take = (tt & 1) ? !qlo : qlo;
                const int kh = tt >> 1;                   // compile-time (unrolled)
                bi[kh][0] = take ? s0 : bi[kh][0];
                bi[kh][1] = take ? s1 : bi[kh][1];
                bi[kh][2] = take ? s2 : bi[kh][2];
                bi[kh][3] = take ? s3 : bi[kh][3];
            } else {
                // FC inline: pfc += h[j_h][e] * W_fc[j_h]
                const f32x4 wfc4 = *(const f32x4*)(wfc_s + tt * 16 + q * 4);
                #pragma unroll
                for (int r = 0; r < 4; r++)
                    pfc = fmaf(hv4[r], wfc4[r], pfc);
            }
        }
    }

    // ---- FC epilogue: reduce over the 4 q-groups (j_h partition), write ----
    pfc += __shfl_xor(pfc, 16, 64);
    pfc += __shfl_xor(pfc, 32, 64);
    if (lane < 16) {
        const int eo = eg0 + lane;
        if (eo < B) out[eo] = pfc + b_fc[0];
    }
}

extern "C" void kernel_launch(void* const* d_in, const int* in_sizes, int n_in,
                              void* d_out, int out_size, void* d_ws, size_t ws_size,
                              hipStream_t stream) {
    const float* x    = (const float*)d_in[0];
    const float* W_ih = (const float*)d_in[1];
    const float* W_hh = (const float*)d_in[2];
    const float* b_ih = (const float*)d_in[3];
    const float* b_hh = (const float*)d_in[4];
    const float* W_fc = (const float*)d_in[5];
    const float* b_fc = (const float*)d_in[6];
    float* out = (float*)d_out;

    const int B = in_sizes[0] / TSTEPS;   // x is [B, T, 1]
    const int grid = (B + EPB - 1) / EPB;
    lstm_mfma_kernel<<<grid, BLOCK, 0, stream>>>(x, W_ih, W_hh, b_ih, b_hh,
                                                 W_fc, b_fc, out, B);
}

// Round 11
// 151.254 us; speedup vs baseline: 4.6006x; 4.5551x over previous
//
#include <hip/hip_runtime.h>

#define HDIM   64
#define TSTEPS 5
#define WAVES  8
#define BLOCK  (WAVES * 64)     // 512 threads
#define EPW    16               // batch per wave = MFMA M
#define EPB    (WAVES * EPW)    // 128 batch per block

typedef _Float16 f16x8 __attribute__((ext_vector_type(8)));
typedef float    f32x4 __attribute__((ext_vector_type(4)));

#define L2E 1.44269504088896340736f   // log2(e)

// Native 1-ulp ops (trans pipe -> minimize count; floor is 5 ex2 + 2 rcp per u)
__device__ __forceinline__ float rcp_(float x) { return __builtin_amdgcn_rcpf(x); }
__device__ __forceinline__ float ex2_(float x) { return __builtin_amdgcn_exp2f(x); }

// ===== ROUND-8 KERNEL (best verified: 103.9 us rocprof, VGPR 60, no spill)
// with ONE change: launch_bounds arg2 4 -> 3 (VGPR cap 64 -> 85).
// Rationale: LDS (51.7 KB -> 3 blocks/CU x 8 waves = 24 waves/CU = 6/SIMD)
// caps residency for ANY VGPR <= 85 (floor(512/85) = 6/SIMD). So cap 85 keeps
// occupancy identical while giving the scheduler ~25 spare regs to pipeline
// across gr iterations (w0/w1 prefetch, activation/MFMA overlap) and eat part
// of the 23% VALU-idle. Spill-safe: the body FITS at 60 under cap 64; a looser
// cap cannot introduce spill. Occupancy-safe: round-4's failure needed VGPR>85.
//
// Gates as D[m=batch e][n=gate row j'] = A[e][k]*B[k][j'] + C(bias + x*W_ih)
// A = h^T (rebuilt per t), B = W_hh^T (staged once, PRE-SCALED by log2e /
// 2*log2e for g columns). 16x16x32 f16 layouts (verified, absmax 9.8e-4):
//   A-frag: lane holds A[m=lane&15][k = kh*32 + (lane>>4)*8 + i], i=0..7
//   B-frag: lane holds B[k = kh*32 + (lane>>4)*8 + i][n = ntile*16 + (lane&15)]
//   C/D:    lane holds D[m = (lane>>4)*4 + reg][n = ntile*16 + (lane&15)]
//
// ACTIVATION (7 trans/u, the floor for this functional form):
//   a  = (1+Ei)(Eg+1);  b = (1+Ef);  rr = rcp(a*b)       // ONE rcp for i&f
//   it = 2L2E*(Eg-1)*(rr*b); sf = rr*a; cs = fmaf(sf,c,it)  [2L2E-scaled c]
//   hn = (Ec-1)*rcp((1+Eo)(Ec+1))                        // o*tanh(c), ONE rcp
//
// CONSTRAINT WEB (rounds 1-10, all measured — do not retry):
//   VGPR cap = 256/arg2 (8->32, 4->64, 3->85, 2->128); allocator expands
//   into the cap when pressured (r4: 124/128).
//   Residency cliff AT 64 VGPR (r6); 65..85 keeps 6/SIMD (LDS-bound anyway).
//   DEAD: WAVES=16 (cliff); global common-denominator activation (live ~95);
//   hoisted coeff arrays (+32 live); TRANSPOSED gates^T=W_hh*h^T formulation
//   (r9/r10: live ~68-75 > 63 -> spill, no allocator setting works);
//   further trans-count cuts (10->8->7 each moved <=2%: issue-neutral swaps).
__global__ __launch_bounds__(BLOCK, 3) void lstm_mfma_kernel(
    const float* __restrict__ x,      // [B, T, 1]
    const float* __restrict__ W_ih,   // [256, 1]
    const float* __restrict__ W_hh,   // [256, 64]
    const float* __restrict__ b_ih,   // [256]
    const float* __restrict__ b_hh,   // [256]
    const float* __restrict__ W_fc,   // [1, 64]
    const float* __restrict__ b_fc,   // [1]
    float* __restrict__ out,          // [B, 1]
    int B)
{
    __shared__ _Float16 Wf[2048 * 8];          // 32 KB, B-fragments, fragment-linear
    __shared__ _Float16 hbuf[WAVES * 1024];    // 16 KB, per-wave h A-fragments
    __shared__ float    wih_s[256];            // 1 KB (pre-scaled)
    __shared__ float    cb_s[256];             // 1 KB (pre-scaled b_ih + b_hh)
    __shared__ float    wfc_s[64];             // 256 B (FC weights)

    const int tid = threadIdx.x;

    // ---- one-time staging: W_hh -> fp16 B-fragments, log2e pre-scaled ----
    #pragma unroll
    for (int s0 = 0; s0 < 2048; s0 += BLOCK) {
        const int s  = s0 + tid;
        const int ln = s & 63;
        const int kh = (s >> 6) & 1;
        const int n  = s >> 7;                             // N-tile 0..15, gate G = n>>2
        const float scl = ((n >> 2) == 2) ? (2.0f * L2E) : L2E;
        const int j  = n * 16 + (ln & 15);                 // gate row j'
        const int k0 = kh * 32 + ((ln >> 4) & 3) * 8;      // hidden k
        const float* src = W_hh + j * HDIM + k0;
        #pragma unroll
        for (int i = 0; i < 8; i++)
            Wf[s * 8 + i] = (_Float16)(src[i] * scl);
    }
    if (tid < 256) {
        const float scl = ((tid >> 6) == 2) ? (2.0f * L2E) : L2E;
        wih_s[tid] = W_ih[tid] * scl;
        cb_s[tid]  = (b_ih[tid] + b_hh[tid]) * scl;
    }
    if (tid < 64) wfc_s[tid] = W_fc[tid];
    __syncthreads();   // only barrier in the kernel

    const int lane = tid & 63;
    const int wave = tid >> 6;
    const int m    = lane & 15;    // C-layout column (gate-row local) / A row m
    const int q    = lane >> 4;    // quad
    const int eg0  = (blockIdx.x * WAVES + wave) * EPW;

    _Float16* hb = hbuf + wave * 1024;

    // Single x base pointer; per-(r,t) loads are compile-time imm offsets.
    // Clamp the 4-row window into [0, B): rows >= B compute garbage on valid
    // memory; the out-write guard drops them.
    int e0 = eg0 + q * 4;
    if (e0 > B - 4) e0 = (B >= 4 ? B - 4 : 0);
    const float* xp0 = x + (long)e0 * TSTEPS;

    float c[16];    // cell state, SCALED by 2*log2e; [gr*4+r] <-> (j=gr*16+m, e=e0+r)
    float pfc[4];   // FC partial sums, defined only in the t=4 body

    #pragma unroll
    for (int t = 0; t < TSTEPS; t++) {
        float xt[4];
        #pragma unroll
        for (int r = 0; r < 4; r++) xt[r] = xp0[r * TSTEPS + t];   // imm offsets

        // h A-fragments from previous timestep (same-wave LDS, no barrier needed)
        f16x8 hA0, hA1;
        if (t > 0) {
            hA0 = *(const f16x8*)(hb + lane * 8);          // kh = 0
            hA1 = *(const f16x8*)(hb + 512 + lane * 8);    // kh = 1
        }

        #pragma unroll
        for (int gr = 0; gr < 4; gr++) {       // j' chunk: j = gr*16 + m
            // C-init: bias + x*W_ih directly as the MFMA C operand
            float wihv[4], cbv[4];
            #pragma unroll
            for (int G = 0; G < 4; G++) {
                wihv[G] = wih_s[G * 64 + gr * 16 + m];   // broadcast, conflict-free
                cbv[G]  = cb_s[G * 64 + gr * 16 + m];
            }
            f32x4 ag[4];
            #pragma unroll
            for (int G = 0; G < 4; G++)
                #pragma unroll
                for (int r = 0; r < 4; r++)
                    ag[G][r] = fmaf(xt[r], wihv[G], cbv[G]);

            if (t > 0) {
                #pragma unroll
                for (int G = 0; G < 4; G++) {
                    const int n = G * 4 + gr;
                    f16x8 w0 = *(const f16x8*)(Wf + (n * 2 + 0) * 512 + lane * 8);
                    f16x8 w1 = *(const f16x8*)(Wf + (n * 2 + 1) * 512 + lane * 8);
                    ag[G] = __builtin_amdgcn_mfma_f32_16x16x32_f16(hA0, w0, ag[G], 0, 0, 0);
                    ag[G] = __builtin_amdgcn_mfma_f32_16x16x32_f16(hA1, w1, ag[G], 0, 0, 0);
                }
            }

            #pragma unroll
            for (int r = 0; r < 4; r++) {
                const int u = gr * 4 + r;
                const float Ei = ex2_(-ag[0][r]);
                const float Eg = ex2_(ag[2][r]);
                const float a  = (1.0f + Ei) * (Eg + 1.0f);
                const float gn = (2.0f * L2E) * (Eg - 1.0f);
                float cs;
                if (t > 0) {
                    // paired rcp: one v_rcp serves both i*tanh(g) and sigmoid(f)
                    const float Ef = ex2_(-ag[1][r]);
                    const float b  = 1.0f + Ef;
                    const float rr = rcp_(a * b);
                    const float it = gn * (rr * b);
                    const float sf = rr * a;
                    cs = fmaf(sf, c[u], it);
                } else {
                    cs = gn * rcp_(a);
                }
                c[u] = cs;                                // scaled domain
                // fused o*tanh(c): 2 ex2 + 1 rcp
                const float Eo = ex2_(-ag[3][r]);
                const float Ec = ex2_(cs);
                const float hn = (Ec - 1.0f) * rcp_((1.0f + Eo) * (Ec + 1.0f));
                if (t < TSTEPS - 1) {
                    // scatter h (fp16) into next timestep's A-fragment slots
                    const int lp = (q * 4 + r) + 16 * (2 * (gr & 1) + (m >> 3));
                    hb[(gr >> 1) * 512 + lp * 8 + (m & 7)] = (_Float16)hn;
                } else {
                    // FC inline: pfc[r] += h[j=gr*16+m][e] * W_fc[j]
                    const float w = wfc_s[gr * 16 + m];
                    pfc[r] = (gr == 0) ? hn * w : fmaf(hn, w, pfc[r]);
                }
            }
        }
    }

    // ---- FC epilogue: reduce pfc over the 16 m-lanes, write out ----
    const float bfc = b_fc[0];
    #pragma unroll
    for (int r = 0; r < 4; r++) {
        float p = pfc[r];
        p += __shfl_xor(p, 1, 64);
        p += __shfl_xor(p, 2, 64);
        p += __shfl_xor(p, 4, 64);
        p += __shfl_xor(p, 8, 64);
        if (m == 0) {
            const int e = e0 + r;
            if (e < B) out[e] = p + bfc;
        }
    }
}

extern "C" void kernel_launch(void* const* d_in, const int* in_sizes, int n_in,
                              void* d_out, int out_size, void* d_ws, size_t ws_size,
                              hipStream_t stream) {
    const float* x    = (const float*)d_in[0];
    const float* W_ih = (const float*)d_in[1];
    const float* W_hh = (const float*)d_in[2];
    const float* b_ih = (const float*)d_in[3];
    const float* b_hh = (const float*)d_in[4];
    const float* W_fc = (const float*)d_in[5];
    const float* b_fc = (const float*)d_in[6];
    float* out = (float*)d_out;

    const int B = in_sizes[0] / TSTEPS;   // x is [B, T, 1]
    const int grid = (B + EPB - 1) / EPB;
    lstm_mfma_kernel<<<grid, BLOCK, 0, stream>>>(x, W_ih, W_hh, b_ih, b_hh,
                                                 W_fc, b_fc, out, B);
}